// Round 1
// baseline (1293.948 us; speedup 1.0000x reference)
//
#include <hip/hip_runtime.h>

#define N_NODES 50000
#define N_EDGES 800000
#define D_IN 128
#define D_H 64

__global__ void count_kernel(const int* __restrict__ dstv, float* __restrict__ cnt) {
    int e = blockIdx.x * blockDim.x + threadIdx.x;
    if (e < N_EDGES) atomicAdd(&cnt[dstv[e]], 1.0f);
}

__global__ void inv_kernel(float* __restrict__ cnt) {
    int i = blockIdx.x * blockDim.x + threadIdx.x;
    if (i < N_NODES) cnt[i] = 1.0f / fmaxf(cnt[i], 1.0f);
}

// one thread per (edge, feature); F is 128 or 64 (power of 2)
template <int F, int LOGF>
__global__ void scatter_kernel(const float* __restrict__ h, const int* __restrict__ srcv,
                               const int* __restrict__ dstv, float* __restrict__ agg) {
    int idx = blockIdx.x * blockDim.x + threadIdx.x;
    if (idx >= N_EDGES * F) return;
    int e = idx >> LOGF;
    int f = idx & (F - 1);
    int s = srcv[e];
    int d = dstv[e];
    atomicAdd(&agg[d * F + f], h[s * F + f]);
}

// out[i,j] = elu( (sum_k agg[i,k]*Wl[k,j]) * inv_cnt[i] + bl[j] + sum_k x[i,k]*Wr[k,j] )
template <int FIN>
__global__ void sage_linear_kernel(const float* __restrict__ agg, const float* __restrict__ x,
                                   const float* __restrict__ inv_cnt,
                                   const float* __restrict__ Wl, const float* __restrict__ bl,
                                   const float* __restrict__ Wr, float* __restrict__ out) {
    int idx = blockIdx.x * blockDim.x + threadIdx.x;
    if (idx >= N_NODES * D_H) return;
    int i = idx >> 6;
    int j = idx & 63;
    const float* __restrict__ arow = agg + (size_t)i * FIN;
    const float* __restrict__ xrow = x + (size_t)i * FIN;
    float acc_a = 0.0f;
    float acc_x = 0.0f;
#pragma unroll 8
    for (int k = 0; k < FIN; ++k) {
        acc_a += arow[k] * Wl[k * D_H + j];
        acc_x += xrow[k] * Wr[k * D_H + j];
    }
    float acc = acc_a * inv_cnt[i] + bl[j] + acc_x;
    out[idx] = acc > 0.0f ? acc : expm1f(acc);
}

// out[e, 0:4] = concat(h[src[e]], h[dst[e]]) @ Wp + bp
__global__ void edge_out_kernel(const float* __restrict__ h, const int* __restrict__ srcv,
                                const int* __restrict__ dstv, const float* __restrict__ Wp,
                                const float* __restrict__ bp, float* __restrict__ out) {
    int e = blockIdx.x * blockDim.x + threadIdx.x;
    if (e >= N_EDGES) return;
    const float* __restrict__ hs = h + (size_t)srcv[e] * D_H;
    const float* __restrict__ hd = h + (size_t)dstv[e] * D_H;
    float a0 = bp[0], a1 = bp[1], a2 = bp[2], a3 = bp[3];
#pragma unroll 8
    for (int k = 0; k < D_H; ++k) {
        float v = hs[k];
        a0 += v * Wp[k * 4 + 0];
        a1 += v * Wp[k * 4 + 1];
        a2 += v * Wp[k * 4 + 2];
        a3 += v * Wp[k * 4 + 3];
    }
#pragma unroll 8
    for (int k = 0; k < D_H; ++k) {
        float v = hd[k];
        a0 += v * Wp[(D_H + k) * 4 + 0];
        a1 += v * Wp[(D_H + k) * 4 + 1];
        a2 += v * Wp[(D_H + k) * 4 + 2];
        a3 += v * Wp[(D_H + k) * 4 + 3];
    }
    float4 o;
    o.x = a0; o.y = a1; o.z = a2; o.w = a3;
    reinterpret_cast<float4*>(out)[e] = o;
}

extern "C" void kernel_launch(void* const* d_in, const int* in_sizes, int n_in,
                              void* d_out, int out_size, void* d_ws, size_t ws_size,
                              hipStream_t stream) {
    const float* x   = (const float*)d_in[0];
    const int*   ei  = (const int*)d_in[1];
    const float* Wl1 = (const float*)d_in[2];
    const float* bl1 = (const float*)d_in[3];
    const float* Wr1 = (const float*)d_in[4];
    const float* Wl2 = (const float*)d_in[5];
    const float* bl2 = (const float*)d_in[6];
    const float* Wr2 = (const float*)d_in[7];
    const float* Wl3 = (const float*)d_in[8];
    const float* bl3 = (const float*)d_in[9];
    const float* Wr3 = (const float*)d_in[10];
    const float* Wp  = (const float*)d_in[11];
    const float* bp  = (const float*)d_in[12];
    float* out = (float*)d_out;

    float* ws      = (float*)d_ws;
    float* agg     = ws;                           // 50000*128 = 6.4M floats
    float* bufA    = agg + (size_t)N_NODES * D_IN; // 3.2M floats
    float* bufB    = bufA + (size_t)N_NODES * D_H; // 3.2M floats
    float* inv_cnt = bufB + (size_t)N_NODES * D_H; // 50000 floats

    const int* srcv = ei;
    const int* dstv = ei + N_EDGES;

    // degree counts -> inverse
    hipMemsetAsync(inv_cnt, 0, N_NODES * sizeof(float), stream);
    count_kernel<<<(N_EDGES + 255) / 256, 256, 0, stream>>>(dstv, inv_cnt);
    inv_kernel<<<(N_NODES + 255) / 256, 256, 0, stream>>>(inv_cnt);

    // ---- layer 1 (FIN = 128) ----
    hipMemsetAsync(agg, 0, (size_t)N_NODES * D_IN * sizeof(float), stream);
    {
        int total = N_EDGES * D_IN;
        scatter_kernel<D_IN, 7><<<(total + 255) / 256, 256, 0, stream>>>(x, srcv, dstv, agg);
    }
    sage_linear_kernel<D_IN><<<(N_NODES * D_H + 255) / 256, 256, 0, stream>>>(
        agg, x, inv_cnt, Wl1, bl1, Wr1, bufA);

    // ---- layer 2 (FIN = 64) ----
    hipMemsetAsync(agg, 0, (size_t)N_NODES * D_H * sizeof(float), stream);
    {
        int total = N_EDGES * D_H;
        scatter_kernel<D_H, 6><<<(total + 255) / 256, 256, 0, stream>>>(bufA, srcv, dstv, agg);
    }
    sage_linear_kernel<D_H><<<(N_NODES * D_H + 255) / 256, 256, 0, stream>>>(
        agg, bufA, inv_cnt, Wl2, bl2, Wr2, bufB);

    // ---- layer 3 (FIN = 64) ----
    hipMemsetAsync(agg, 0, (size_t)N_NODES * D_H * sizeof(float), stream);
    {
        int total = N_EDGES * D_H;
        scatter_kernel<D_H, 6><<<(total + 255) / 256, 256, 0, stream>>>(bufB, srcv, dstv, agg);
    }
    sage_linear_kernel<D_H><<<(N_NODES * D_H + 255) / 256, 256, 0, stream>>>(
        agg, bufB, inv_cnt, Wl3, bl3, Wr3, bufA);

    // ---- edge output ----
    edge_out_kernel<<<(N_EDGES + 255) / 256, 256, 0, stream>>>(bufA, srcv, dstv, Wp, bp, out);
}

// Round 2
// 628.770 us; speedup vs baseline: 2.0579x; 2.0579x over previous
//
#include <hip/hip_runtime.h>

#define N_NODES 50000
#define N_EDGES 800000
#define D_IN 128
#define D_H 64
#define SCAN_BLOCKS 196   // ceil(50000/256)

// ---------- CSR build ----------
__global__ void hist_kernel(const int* __restrict__ dstv, int* __restrict__ cnt) {
    int e = blockIdx.x * 256 + threadIdx.x;
    if (e < N_EDGES) atomicAdd(&cnt[dstv[e]], 1);
}

__global__ void scan_partial(const int* __restrict__ cnt, int* __restrict__ blockSums) {
    __shared__ int s[256];
    int i = blockIdx.x * 256 + threadIdx.x;
    s[threadIdx.x] = (i < N_NODES) ? cnt[i] : 0;
    __syncthreads();
    for (int off = 128; off > 0; off >>= 1) {
        if (threadIdx.x < off) s[threadIdx.x] += s[threadIdx.x + off];
        __syncthreads();
    }
    if (threadIdx.x == 0) blockSums[blockIdx.x] = s[0];
}

__global__ void scan_sums(int* __restrict__ blockSums) {
    __shared__ int s[256];
    int t = threadIdx.x;
    s[t] = (t < SCAN_BLOCKS) ? blockSums[t] : 0;
    __syncthreads();
    for (int off = 1; off < 256; off <<= 1) {
        int tmp = (t >= off) ? s[t - off] : 0;
        __syncthreads();
        s[t] += tmp;
        __syncthreads();
    }
    if (t < SCAN_BLOCKS) blockSums[t] = (t > 0) ? s[t - 1] : 0;
}

__global__ void scan_final(const int* __restrict__ cnt, const int* __restrict__ blockSums,
                           int* __restrict__ row_ptr, int* __restrict__ cursor) {
    __shared__ int s[256];
    int t = threadIdx.x;
    int i = blockIdx.x * 256 + t;
    s[t] = (i < N_NODES) ? cnt[i] : 0;
    __syncthreads();
    for (int off = 1; off < 256; off <<= 1) {
        int tmp = (t >= off) ? s[t - off] : 0;
        __syncthreads();
        s[t] += tmp;
        __syncthreads();
    }
    int excl = blockSums[blockIdx.x] + ((t > 0) ? s[t - 1] : 0);
    if (i < N_NODES) { row_ptr[i] = excl; cursor[i] = excl; }
    if (i == 0) row_ptr[N_NODES] = N_EDGES;
}

__global__ void fill_kernel(const int* __restrict__ srcv, const int* __restrict__ dstv,
                            int* __restrict__ cursor, int* __restrict__ csr_src) {
    int e = blockIdx.x * 256 + threadIdx.x;
    if (e < N_EDGES) {
        int pos = atomicAdd(&cursor[dstv[e]], 1);
        csr_src[pos] = srcv[e];
    }
}

// ---------- Y = h @ Wl  (pre-transform; aggregation is linear) ----------
template <int FIN>
__global__ void lin_kernel(const float* __restrict__ h, const float* __restrict__ Wl,
                           float* __restrict__ Y) {
    int idx = blockIdx.x * 256 + threadIdx.x;
    if (idx >= N_NODES * D_H) return;
    int i = idx >> 6, j = idx & 63;
    const float* __restrict__ hr = h + (size_t)i * FIN;
    float acc = 0.0f;
#pragma unroll 8
    for (int k = 0; k < FIN; ++k) acc += hr[k] * Wl[k * D_H + j];
    Y[idx] = acc;
}

// ---------- per-node: z = h@Wr; agg = mean of Y[src]; out = elu(agg + bl + z) ----------
// one wave per node, lane = output feature
template <int FIN>
__global__ void gather_kernel(const float* __restrict__ Y, const float* __restrict__ h_in,
                              const float* __restrict__ Wr, const float* __restrict__ bl,
                              const int* __restrict__ row_ptr, const int* __restrict__ csr_src,
                              float* __restrict__ out) {
    int node = (blockIdx.x << 2) + (threadIdx.x >> 6);
    int lane = threadIdx.x & 63;
    if (node >= N_NODES) return;

    const float* __restrict__ hr = h_in + (size_t)node * FIN;
    float z = 0.0f;
#pragma unroll 8
    for (int k = 0; k < FIN; ++k) z += hr[k] * Wr[k * D_H + lane];

    int beg = row_ptr[node], end = row_ptr[node + 1];
    float acc = 0.0f;
    int k = beg;
    for (; k + 3 < end; k += 4) {
        int s0 = csr_src[k], s1 = csr_src[k + 1], s2 = csr_src[k + 2], s3 = csr_src[k + 3];
        acc += Y[s0 * D_H + lane];
        acc += Y[s1 * D_H + lane];
        acc += Y[s2 * D_H + lane];
        acc += Y[s3 * D_H + lane];
    }
    for (; k < end; ++k) acc += Y[csr_src[k] * D_H + lane];

    float inv = 1.0f / fmaxf((float)(end - beg), 1.0f);
    float v = acc * inv + bl[lane] + z;
    out[(size_t)node * D_H + lane] = v > 0.0f ? v : expm1f(v);
}

// ---------- ps = h @ Wp[0:64], pd = h @ Wp[64:128] ----------
__global__ void proj_kernel(const float* __restrict__ h, const float* __restrict__ Wp,
                            float* __restrict__ ps, float* __restrict__ pd) {
    int idx = blockIdx.x * 256 + threadIdx.x;
    if (idx >= N_NODES * 4) return;
    int i = idx >> 2, c = idx & 3;
    const float* __restrict__ hr = h + (size_t)i * D_H;
    float a = 0.0f, b = 0.0f;
#pragma unroll 8
    for (int k = 0; k < D_H; ++k) {
        a += hr[k] * Wp[k * 4 + c];
        b += hr[k] * Wp[(D_H + k) * 4 + c];
    }
    ps[idx] = a;
    pd[idx] = b;
}

__global__ void edge_final_kernel(const int* __restrict__ srcv, const int* __restrict__ dstv,
                                  const float* __restrict__ ps, const float* __restrict__ pd,
                                  const float* __restrict__ bp, float* __restrict__ out) {
    int e = blockIdx.x * 256 + threadIdx.x;
    if (e >= N_EDGES) return;
    float4 a = reinterpret_cast<const float4*>(ps)[srcv[e]];
    float4 b = reinterpret_cast<const float4*>(pd)[dstv[e]];
    float4 o;
    o.x = a.x + b.x + bp[0];
    o.y = a.y + b.y + bp[1];
    o.z = a.z + b.z + bp[2];
    o.w = a.w + b.w + bp[3];
    reinterpret_cast<float4*>(out)[e] = o;
}

extern "C" void kernel_launch(void* const* d_in, const int* in_sizes, int n_in,
                              void* d_out, int out_size, void* d_ws, size_t ws_size,
                              hipStream_t stream) {
    const float* x   = (const float*)d_in[0];
    const int*   ei  = (const int*)d_in[1];
    const float* Wl1 = (const float*)d_in[2];
    const float* bl1 = (const float*)d_in[3];
    const float* Wr1 = (const float*)d_in[4];
    const float* Wl2 = (const float*)d_in[5];
    const float* bl2 = (const float*)d_in[6];
    const float* Wr2 = (const float*)d_in[7];
    const float* Wl3 = (const float*)d_in[8];
    const float* bl3 = (const float*)d_in[9];
    const float* Wr3 = (const float*)d_in[10];
    const float* Wp  = (const float*)d_in[11];
    const float* bp  = (const float*)d_in[12];
    float* out = (float*)d_out;

    const int* srcv = ei;
    const int* dstv = ei + N_EDGES;

    // ---- workspace carve-up (ints first, then floats; all 16B-aligned) ----
    int*   cnt       = (int*)d_ws;                     // 50000
    int*   blockSums = cnt + 50000;                    // 256
    int*   row_ptr   = blockSums + 256;                // 50001
    int*   cursor    = row_ptr + 50001;                // 50000
    int*   csr_src   = cursor + 50000;                 // 800000
    float* Y         = (float*)(csr_src + 800000 + 15);// pad to keep 16B align
    // realign to 16 bytes
    Y = (float*)(((uintptr_t)(csr_src + 800000) + 15) & ~(uintptr_t)15);
    float* H1 = Y  + (size_t)N_NODES * D_H;            // 3.2M
    float* H2 = H1 + (size_t)N_NODES * D_H;            // 3.2M
    float* ps = H2 + (size_t)N_NODES * D_H;            // 200000
    float* pd = ps + (size_t)N_NODES * 4;              // 200000

    // ---- CSR build ----
    hipMemsetAsync(cnt, 0, N_NODES * sizeof(int), stream);
    hist_kernel<<<(N_EDGES + 255) / 256, 256, 0, stream>>>(dstv, cnt);
    scan_partial<<<SCAN_BLOCKS, 256, 0, stream>>>(cnt, blockSums);
    scan_sums<<<1, 256, 0, stream>>>(blockSums);
    scan_final<<<SCAN_BLOCKS, 256, 0, stream>>>(cnt, blockSums, row_ptr, cursor);
    fill_kernel<<<(N_EDGES + 255) / 256, 256, 0, stream>>>(srcv, dstv, cursor, csr_src);

    const int LIN_GRID = (N_NODES * D_H + 255) / 256;
    const int GATHER_GRID = (N_NODES + 3) / 4;

    // ---- layer 1 (FIN=128) ----
    lin_kernel<D_IN><<<LIN_GRID, 256, 0, stream>>>(x, Wl1, Y);
    gather_kernel<D_IN><<<GATHER_GRID, 256, 0, stream>>>(Y, x, Wr1, bl1, row_ptr, csr_src, H1);

    // ---- layer 2 (FIN=64) ----
    lin_kernel<D_H><<<LIN_GRID, 256, 0, stream>>>(H1, Wl2, Y);
    gather_kernel<D_H><<<GATHER_GRID, 256, 0, stream>>>(Y, H1, Wr2, bl2, row_ptr, csr_src, H2);

    // ---- layer 3 (FIN=64) ----
    lin_kernel<D_H><<<LIN_GRID, 256, 0, stream>>>(H2, Wl3, Y);
    gather_kernel<D_H><<<GATHER_GRID, 256, 0, stream>>>(Y, H2, Wr3, bl3, row_ptr, csr_src, H1);

    // ---- edge output: out[e] = ps[src] + pd[dst] + bp ----
    proj_kernel<<<(N_NODES * 4 + 255) / 256, 256, 0, stream>>>(H1, Wp, ps, pd);
    edge_final_kernel<<<(N_EDGES + 255) / 256, 256, 0, stream>>>(srcv, dstv, ps, pd, bp, out);
}

// Round 3
// 551.138 us; speedup vs baseline: 2.3478x; 1.1409x over previous
//
#include <hip/hip_runtime.h>
#include <hip/hip_bf16.h>

#define N_NODES 50000
#define N_EDGES 800000
#define D_IN 128
#define D_H 64
#define SCAN_BLOCKS 196   // ceil(50000/256)

// ---------- CSR build ----------
__global__ void hist_kernel(const int* __restrict__ dstv, int* __restrict__ cnt) {
    int e = blockIdx.x * 256 + threadIdx.x;
    if (e < N_EDGES) atomicAdd(&cnt[dstv[e]], 1);
}

__global__ void scan_partial(const int* __restrict__ cnt, int* __restrict__ blockSums) {
    __shared__ int s[256];
    int i = blockIdx.x * 256 + threadIdx.x;
    s[threadIdx.x] = (i < N_NODES) ? cnt[i] : 0;
    __syncthreads();
    for (int off = 128; off > 0; off >>= 1) {
        if (threadIdx.x < off) s[threadIdx.x] += s[threadIdx.x + off];
        __syncthreads();
    }
    if (threadIdx.x == 0) blockSums[blockIdx.x] = s[0];
}

__global__ void scan_sums(int* __restrict__ blockSums) {
    __shared__ int s[256];
    int t = threadIdx.x;
    s[t] = (t < SCAN_BLOCKS) ? blockSums[t] : 0;
    __syncthreads();
    for (int off = 1; off < 256; off <<= 1) {
        int tmp = (t >= off) ? s[t - off] : 0;
        __syncthreads();
        s[t] += tmp;
        __syncthreads();
    }
    if (t < SCAN_BLOCKS) blockSums[t] = (t > 0) ? s[t - 1] : 0;
}

__global__ void scan_final(const int* __restrict__ cnt, const int* __restrict__ blockSums,
                           int* __restrict__ row_ptr, int* __restrict__ cursor) {
    __shared__ int s[256];
    int t = threadIdx.x;
    int i = blockIdx.x * 256 + t;
    s[t] = (i < N_NODES) ? cnt[i] : 0;
    __syncthreads();
    for (int off = 1; off < 256; off <<= 1) {
        int tmp = (t >= off) ? s[t - off] : 0;
        __syncthreads();
        s[t] += tmp;
        __syncthreads();
    }
    int excl = blockSums[blockIdx.x] + ((t > 0) ? s[t - 1] : 0);
    if (i < N_NODES) { row_ptr[i] = excl; cursor[i] = excl; }
    if (i == 0) row_ptr[N_NODES] = N_EDGES;
}

__global__ void fill_kernel(const int* __restrict__ srcv, const int* __restrict__ dstv,
                            int* __restrict__ cursor, int* __restrict__ csr_src) {
    int e = blockIdx.x * 256 + threadIdx.x;
    if (e < N_EDGES) {
        int pos = atomicAdd(&cursor[dstv[e]], 1);
        csr_src[pos] = srcv[e];
    }
}

// ---------- Y = bf16(h @ Wl)  (pre-transform; aggregation is linear) ----------
template <int FIN>
__global__ void lin_kernel(const float* __restrict__ h, const float* __restrict__ Wl,
                           __hip_bfloat16* __restrict__ Y) {
    int idx = blockIdx.x * 256 + threadIdx.x;
    if (idx >= N_NODES * D_H) return;
    int i = idx >> 6, j = idx & 63;
    const float* __restrict__ hr = h + (size_t)i * FIN;
    float acc = 0.0f;
#pragma unroll 8
    for (int k = 0; k < FIN; ++k) acc += hr[k] * Wl[k * D_H + j];
    Y[idx] = __float2bfloat16(acc);
}

__device__ __forceinline__ float bf16_lo(unsigned int u) {
    return __uint_as_float(u << 16);
}
__device__ __forceinline__ float bf16_hi(unsigned int u) {
    return __uint_as_float(u & 0xffff0000u);
}

// ---------- per-node fused: z = h@Wr; agg = mean_{src} Y[src]; out = elu(agg+bl+z) ----------
// one wave per node; lane = g*16+l : group g handles edge (k+g), lane-chunk l covers
// features [4l, 4l+4) via one 8-byte (4 x bf16) load. Row = 128B = one cache line.
template <int FIN>
__global__ void gather_kernel(const __hip_bfloat16* __restrict__ Y,
                              const float* __restrict__ h_in,
                              const float* __restrict__ Wr, const float* __restrict__ bl,
                              const int* __restrict__ row_ptr, const int* __restrict__ csr_src,
                              float* __restrict__ out) {
    int node = (blockIdx.x << 2) + (threadIdx.x >> 6);
    int lane = threadIdx.x & 63;
    if (node >= N_NODES) return;
    int g = lane >> 4;    // 0..3
    int l = lane & 15;    // 0..15, features 4l..4l+3

    // z-path: split K across the 4 groups; each lane computes 4 output features
    const float* __restrict__ hr = h_in + (size_t)node * FIN;
    float z0 = 0.f, z1 = 0.f, z2 = 0.f, z3 = 0.f;
    const int KB = FIN / 4;
#pragma unroll 4
    for (int kk = 0; kk < KB; ++kk) {
        int k = g * KB + kk;
        float hv = hr[k];
        float4 wv = reinterpret_cast<const float4*>(Wr + k * D_H)[l];
        z0 += hv * wv.x; z1 += hv * wv.y; z2 += hv * wv.z; z3 += hv * wv.w;
    }

    int beg = row_ptr[node];
    int deg = row_ptr[node + 1] - beg;
    float a0 = 0.f, a1 = 0.f, a2 = 0.f, a3 = 0.f;
    const uint2* __restrict__ Y2 = reinterpret_cast<const uint2*>(Y);  // 16 uint2 per row

    for (int base = 0; base < deg; base += 64) {
        int wend = deg - base; if (wend > 64) wend = 64;
        int mye = base + lane;
        int idxv = (mye < deg) ? csr_src[beg + mye] : 0;
        for (int k = 0; k < wend; k += 8) {
            int e0 = k + g;
            int e1 = k + 4 + g;
            int s0 = __shfl(idxv, e0);
            int s1 = __shfl(idxv, e1);
            bool v0 = e0 < wend, v1 = e1 < wend;
            uint2 r0, r1;
            if (v0) r0 = Y2[s0 * 16 + l];
            if (v1) r1 = Y2[s1 * 16 + l];
            if (v0) {
                a0 += bf16_lo(r0.x); a1 += bf16_hi(r0.x);
                a2 += bf16_lo(r0.y); a3 += bf16_hi(r0.y);
            }
            if (v1) {
                a0 += bf16_lo(r1.x); a1 += bf16_hi(r1.x);
                a2 += bf16_lo(r1.y); a3 += bf16_hi(r1.y);
            }
        }
    }

    // reduce over the 4 groups (lanes differing in bits 4,5)
    a0 += __shfl_xor(a0, 16); a0 += __shfl_xor(a0, 32);
    a1 += __shfl_xor(a1, 16); a1 += __shfl_xor(a1, 32);
    a2 += __shfl_xor(a2, 16); a2 += __shfl_xor(a2, 32);
    a3 += __shfl_xor(a3, 16); a3 += __shfl_xor(a3, 32);
    z0 += __shfl_xor(z0, 16); z0 += __shfl_xor(z0, 32);
    z1 += __shfl_xor(z1, 16); z1 += __shfl_xor(z1, 32);
    z2 += __shfl_xor(z2, 16); z2 += __shfl_xor(z2, 32);
    z3 += __shfl_xor(z3, 16); z3 += __shfl_xor(z3, 32);

    if (g == 0) {
        float inv = 1.0f / fmaxf((float)deg, 1.0f);
        float4 b = reinterpret_cast<const float4*>(bl)[l];
        float v0 = a0 * inv + b.x + z0;
        float v1 = a1 * inv + b.y + z1;
        float v2 = a2 * inv + b.z + z2;
        float v3 = a3 * inv + b.w + z3;
        float4 o;
        o.x = v0 > 0.f ? v0 : expm1f(v0);
        o.y = v1 > 0.f ? v1 : expm1f(v1);
        o.z = v2 > 0.f ? v2 : expm1f(v2);
        o.w = v3 > 0.f ? v3 : expm1f(v3);
        reinterpret_cast<float4*>(out + (size_t)node * D_H)[l] = o;
    }
}

// ---------- ps = h @ Wp[0:64], pd = h @ Wp[64:128] ----------
__global__ void proj_kernel(const float* __restrict__ h, const float* __restrict__ Wp,
                            float* __restrict__ ps, float* __restrict__ pd) {
    int idx = blockIdx.x * 256 + threadIdx.x;
    if (idx >= N_NODES * 4) return;
    int i = idx >> 2, c = idx & 3;
    const float* __restrict__ hr = h + (size_t)i * D_H;
    float a = 0.0f, b = 0.0f;
#pragma unroll 8
    for (int k = 0; k < D_H; ++k) {
        a += hr[k] * Wp[k * 4 + c];
        b += hr[k] * Wp[(D_H + k) * 4 + c];
    }
    ps[idx] = a;
    pd[idx] = b;
}

__global__ void edge_final_kernel(const int* __restrict__ srcv, const int* __restrict__ dstv,
                                  const float* __restrict__ ps, const float* __restrict__ pd,
                                  const float* __restrict__ bp, float* __restrict__ out) {
    int e = blockIdx.x * 256 + threadIdx.x;
    if (e >= N_EDGES) return;
    float4 a = reinterpret_cast<const float4*>(ps)[srcv[e]];
    float4 b = reinterpret_cast<const float4*>(pd)[dstv[e]];
    float4 o;
    o.x = a.x + b.x + bp[0];
    o.y = a.y + b.y + bp[1];
    o.z = a.z + b.z + bp[2];
    o.w = a.w + b.w + bp[3];
    reinterpret_cast<float4*>(out)[e] = o;
}

extern "C" void kernel_launch(void* const* d_in, const int* in_sizes, int n_in,
                              void* d_out, int out_size, void* d_ws, size_t ws_size,
                              hipStream_t stream) {
    const float* x   = (const float*)d_in[0];
    const int*   ei  = (const int*)d_in[1];
    const float* Wl1 = (const float*)d_in[2];
    const float* bl1 = (const float*)d_in[3];
    const float* Wr1 = (const float*)d_in[4];
    const float* Wl2 = (const float*)d_in[5];
    const float* bl2 = (const float*)d_in[6];
    const float* Wr2 = (const float*)d_in[7];
    const float* Wl3 = (const float*)d_in[8];
    const float* bl3 = (const float*)d_in[9];
    const float* Wr3 = (const float*)d_in[10];
    const float* Wp  = (const float*)d_in[11];
    const float* bp  = (const float*)d_in[12];
    float* out = (float*)d_out;

    const int* srcv = ei;
    const int* dstv = ei + N_EDGES;

    // ---- workspace carve-up ----
    int*   cnt       = (int*)d_ws;                     // 50000
    int*   blockSums = cnt + 50000;                    // 256
    int*   row_ptr   = blockSums + 256;                // 50001
    int*   cursor    = row_ptr + 50001;                // 50000
    int*   csr_src   = cursor + 50000;                 // 800000
    __hip_bfloat16* Y = (__hip_bfloat16*)(((uintptr_t)(csr_src + 800000) + 127) & ~(uintptr_t)127);
    float* H1 = (float*)(((uintptr_t)(Y + (size_t)N_NODES * D_H) + 15) & ~(uintptr_t)15);
    float* H2 = H1 + (size_t)N_NODES * D_H;            // 3.2M floats
    float* ps = H2 + (size_t)N_NODES * D_H;            // 200000
    float* pd = ps + (size_t)N_NODES * 4;              // 200000

    // ---- CSR build ----
    hipMemsetAsync(cnt, 0, N_NODES * sizeof(int), stream);
    hist_kernel<<<(N_EDGES + 255) / 256, 256, 0, stream>>>(dstv, cnt);
    scan_partial<<<SCAN_BLOCKS, 256, 0, stream>>>(cnt, blockSums);
    scan_sums<<<1, 256, 0, stream>>>(blockSums);
    scan_final<<<SCAN_BLOCKS, 256, 0, stream>>>(cnt, blockSums, row_ptr, cursor);
    fill_kernel<<<(N_EDGES + 255) / 256, 256, 0, stream>>>(srcv, dstv, cursor, csr_src);

    const int LIN_GRID = (N_NODES * D_H + 255) / 256;
    const int GATHER_GRID = (N_NODES + 3) / 4;

    // ---- layer 1 (FIN=128) ----
    lin_kernel<D_IN><<<LIN_GRID, 256, 0, stream>>>(x, Wl1, Y);
    gather_kernel<D_IN><<<GATHER_GRID, 256, 0, stream>>>(Y, x, Wr1, bl1, row_ptr, csr_src, H1);

    // ---- layer 2 (FIN=64) ----
    lin_kernel<D_H><<<LIN_GRID, 256, 0, stream>>>(H1, Wl2, Y);
    gather_kernel<D_H><<<GATHER_GRID, 256, 0, stream>>>(Y, H1, Wr2, bl2, row_ptr, csr_src, H2);

    // ---- layer 3 (FIN=64) ----
    lin_kernel<D_H><<<LIN_GRID, 256, 0, stream>>>(H2, Wl3, Y);
    gather_kernel<D_H><<<GATHER_GRID, 256, 0, stream>>>(Y, H2, Wr3, bl3, row_ptr, csr_src, H1);

    // ---- edge output: out[e] = ps[src] + pd[dst] + bp ----
    proj_kernel<<<(N_NODES * 4 + 255) / 256, 256, 0, stream>>>(H1, Wp, ps, pd);
    edge_final_kernel<<<(N_EDGES + 255) / 256, 256, 0, stream>>>(srcv, dstv, ps, pd, bp, out);
}

// Round 4
// 393.869 us; speedup vs baseline: 3.2852x; 1.3993x over previous
//
#include <hip/hip_runtime.h>
#include <hip/hip_bf16.h>

#define N_NODES 50000
#define N_EDGES 800000
#define D_IN 128
#define D_H 64
#define SCAN_BLOCKS 196   // ceil(50000/256)

typedef short bf16x8 __attribute__((ext_vector_type(8)));
typedef float f32x4 __attribute__((ext_vector_type(4)));

__device__ __forceinline__ ushort f2bf(float f) {
    __hip_bfloat16 b = __float2bfloat16(f);
    return *reinterpret_cast<ushort*>(&b);
}
__device__ __forceinline__ float bf16_lo(unsigned int u) { return __uint_as_float(u << 16); }
__device__ __forceinline__ float bf16_hi(unsigned int u) { return __uint_as_float(u & 0xffff0000u); }

// ---------- CSR build ----------
__global__ void hist_kernel(const int* __restrict__ dstv, int* __restrict__ cnt) {
    int e = blockIdx.x * 256 + threadIdx.x;
    if (e < N_EDGES) atomicAdd(&cnt[dstv[e]], 1);
}

__global__ void scan_partial(const int* __restrict__ cnt, int* __restrict__ blockSums) {
    __shared__ int s[256];
    int i = blockIdx.x * 256 + threadIdx.x;
    s[threadIdx.x] = (i < N_NODES) ? cnt[i] : 0;
    __syncthreads();
    for (int off = 128; off > 0; off >>= 1) {
        if (threadIdx.x < off) s[threadIdx.x] += s[threadIdx.x + off];
        __syncthreads();
    }
    if (threadIdx.x == 0) blockSums[blockIdx.x] = s[0];
}

__global__ void scan_sums(int* __restrict__ blockSums) {
    __shared__ int s[256];
    int t = threadIdx.x;
    s[t] = (t < SCAN_BLOCKS) ? blockSums[t] : 0;
    __syncthreads();
    for (int off = 1; off < 256; off <<= 1) {
        int tmp = (t >= off) ? s[t - off] : 0;
        __syncthreads();
        s[t] += tmp;
        __syncthreads();
    }
    if (t < SCAN_BLOCKS) blockSums[t] = (t > 0) ? s[t - 1] : 0;
}

__global__ void scan_final(const int* __restrict__ cnt, const int* __restrict__ blockSums,
                           int* __restrict__ row_ptr, int* __restrict__ cursor) {
    __shared__ int s[256];
    int t = threadIdx.x;
    int i = blockIdx.x * 256 + t;
    s[t] = (i < N_NODES) ? cnt[i] : 0;
    __syncthreads();
    for (int off = 1; off < 256; off <<= 1) {
        int tmp = (t >= off) ? s[t - off] : 0;
        __syncthreads();
        s[t] += tmp;
        __syncthreads();
    }
    int excl = blockSums[blockIdx.x] + ((t > 0) ? s[t - 1] : 0);
    if (i < N_NODES) { row_ptr[i] = excl; cursor[i] = excl; }
    if (i == 0) row_ptr[N_NODES] = N_EDGES;
}

__global__ void fill_kernel(const int* __restrict__ srcv, const int* __restrict__ dstv,
                            int* __restrict__ cursor, int* __restrict__ csr_src) {
    int e = blockIdx.x * 256 + threadIdx.x;
    if (e < N_EDGES) {
        int pos = atomicAdd(&cursor[dstv[e]], 1);
        csr_src[pos] = srcv[e];
    }
}

// ---------- fp32 -> bf16 bulk convert (x only) ----------
__global__ void cvt_bf16_kernel(const float* __restrict__ in, ushort* __restrict__ outb, int n4) {
    int i = blockIdx.x * 256 + threadIdx.x;
    if (i >= n4) return;
    float4 v = reinterpret_cast<const float4*>(in)[i];
    ushort4 o;
    o.x = f2bf(v.x); o.y = f2bf(v.y); o.z = f2bf(v.z); o.w = f2bf(v.w);
    reinterpret_cast<ushort4*>(outb)[i] = o;
}

// ---------- Y = bf16(h @ Wl) via MFMA ----------
// wave = one 16-row M-tile (grid-strided), all 64 output cols (4 n-tiles).
// A-frag: lane holds h[m0 + (lane&15)][kt*32 + (lane>>4)*8 + j], j=0..7 (16B load)
// B-frag: lane holds Wl[kt*32 + (lane>>4)*8 + j][nt*16 + (lane&15)] (built once, VGPR-resident)
// D:      lane holds out[m0 + (lane>>4)*4 + reg][nt*16 + (lane&15)]
template <int FIN>
__global__ void lin_mfma_kernel(const ushort* __restrict__ hb, const float* __restrict__ Wl,
                                ushort* __restrict__ Y) {
    constexpr int KT = FIN / 32;
    int wave = (blockIdx.x * 256 + threadIdx.x) >> 6;
    int lane = threadIdx.x & 63;
    int col = lane & 15;
    int quad = lane >> 4;
    int nwaves = gridDim.x * 4;

    bf16x8 bfrag[KT][4];
#pragma unroll
    for (int kt = 0; kt < KT; ++kt)
#pragma unroll
        for (int nt = 0; nt < 4; ++nt) {
            bf16x8 t;
#pragma unroll
            for (int j = 0; j < 8; ++j)
                t[j] = (short)f2bf(Wl[(kt * 32 + quad * 8 + j) * D_H + nt * 16 + col]);
            bfrag[kt][nt] = t;
        }

    for (int m0 = wave * 16; m0 < N_NODES; m0 += nwaves * 16) {
        f32x4 acc0 = {0.f, 0.f, 0.f, 0.f};
        f32x4 acc1 = acc0, acc2 = acc0, acc3 = acc0;
        const ushort* arow = hb + (size_t)(m0 + col) * FIN + quad * 8;
#pragma unroll
        for (int kt = 0; kt < KT; ++kt) {
            bf16x8 a = __builtin_bit_cast(bf16x8,
                *reinterpret_cast<const uint4*>(arow + kt * 32));
            acc0 = __builtin_amdgcn_mfma_f32_16x16x32_bf16(a, bfrag[kt][0], acc0, 0, 0, 0);
            acc1 = __builtin_amdgcn_mfma_f32_16x16x32_bf16(a, bfrag[kt][1], acc1, 0, 0, 0);
            acc2 = __builtin_amdgcn_mfma_f32_16x16x32_bf16(a, bfrag[kt][2], acc2, 0, 0, 0);
            acc3 = __builtin_amdgcn_mfma_f32_16x16x32_bf16(a, bfrag[kt][3], acc3, 0, 0, 0);
        }
#pragma unroll
        for (int reg = 0; reg < 4; ++reg) {
            ushort* yp = Y + (size_t)(m0 + quad * 4 + reg) * D_H;
            yp[0 * 16 + col] = f2bf(acc0[reg]);
            yp[1 * 16 + col] = f2bf(acc1[reg]);
            yp[2 * 16 + col] = f2bf(acc2[reg]);
            yp[3 * 16 + col] = f2bf(acc3[reg]);
        }
    }
}

// ---------- per-node fused: z = h@Wr; agg = mean_{src} Y[src]; out = elu(agg+bl+z) ----------
template <int FIN>
__global__ void gather_kernel(const ushort* __restrict__ Y,
                              const float* __restrict__ h_in,
                              const float* __restrict__ Wr, const float* __restrict__ bl,
                              const int* __restrict__ row_ptr, const int* __restrict__ csr_src,
                              float* __restrict__ out, ushort* __restrict__ outb) {
    int node = (blockIdx.x << 2) + (threadIdx.x >> 6);
    int lane = threadIdx.x & 63;
    if (node >= N_NODES) return;
    int g = lane >> 4;
    int l = lane & 15;

    const float* __restrict__ hr = h_in + (size_t)node * FIN;
    float z0 = 0.f, z1 = 0.f, z2 = 0.f, z3 = 0.f;
    const int KB = FIN / 4;
#pragma unroll 4
    for (int kk = 0; kk < KB; ++kk) {
        int k = g * KB + kk;
        float hv = hr[k];
        float4 wv = reinterpret_cast<const float4*>(Wr + k * D_H)[l];
        z0 += hv * wv.x; z1 += hv * wv.y; z2 += hv * wv.z; z3 += hv * wv.w;
    }

    int beg = row_ptr[node];
    int deg = row_ptr[node + 1] - beg;
    float a0 = 0.f, a1 = 0.f, a2 = 0.f, a3 = 0.f;
    const uint2* __restrict__ Y2 = reinterpret_cast<const uint2*>(Y);  // 16 uint2 per row

    for (int base = 0; base < deg; base += 64) {
        int wend = deg - base; if (wend > 64) wend = 64;
        int mye = base + lane;
        int idxv = (mye < deg) ? csr_src[beg + mye] : 0;
        for (int k = 0; k < wend; k += 8) {
            int e0 = k + g;
            int e1 = k + 4 + g;
            int s0 = __shfl(idxv, e0);
            int s1 = __shfl(idxv, e1);
            bool v0 = e0 < wend, v1 = e1 < wend;
            uint2 r0, r1;
            if (v0) r0 = Y2[s0 * 16 + l];
            if (v1) r1 = Y2[s1 * 16 + l];
            if (v0) {
                a0 += bf16_lo(r0.x); a1 += bf16_hi(r0.x);
                a2 += bf16_lo(r0.y); a3 += bf16_hi(r0.y);
            }
            if (v1) {
                a0 += bf16_lo(r1.x); a1 += bf16_hi(r1.x);
                a2 += bf16_lo(r1.y); a3 += bf16_hi(r1.y);
            }
        }
    }

    a0 += __shfl_xor(a0, 16); a0 += __shfl_xor(a0, 32);
    a1 += __shfl_xor(a1, 16); a1 += __shfl_xor(a1, 32);
    a2 += __shfl_xor(a2, 16); a2 += __shfl_xor(a2, 32);
    a3 += __shfl_xor(a3, 16); a3 += __shfl_xor(a3, 32);
    z0 += __shfl_xor(z0, 16); z0 += __shfl_xor(z0, 32);
    z1 += __shfl_xor(z1, 16); z1 += __shfl_xor(z1, 32);
    z2 += __shfl_xor(z2, 16); z2 += __shfl_xor(z2, 32);
    z3 += __shfl_xor(z3, 16); z3 += __shfl_xor(z3, 32);

    if (g == 0) {
        float inv = 1.0f / fmaxf((float)deg, 1.0f);
        float4 b = reinterpret_cast<const float4*>(bl)[l];
        float v0 = a0 * inv + b.x + z0;
        float v1 = a1 * inv + b.y + z1;
        float v2 = a2 * inv + b.z + z2;
        float v3 = a3 * inv + b.w + z3;
        float4 o;
        o.x = v0 > 0.f ? v0 : expm1f(v0);
        o.y = v1 > 0.f ? v1 : expm1f(v1);
        o.z = v2 > 0.f ? v2 : expm1f(v2);
        o.w = v3 > 0.f ? v3 : expm1f(v3);
        reinterpret_cast<float4*>(out + (size_t)node * D_H)[l] = o;
        ushort4 ob;
        ob.x = f2bf(o.x); ob.y = f2bf(o.y); ob.z = f2bf(o.z); ob.w = f2bf(o.w);
        reinterpret_cast<ushort4*>(outb + (size_t)node * D_H)[l] = ob;
    }
}

// ---------- ps = h @ Wp[0:64], pd = h @ Wp[64:128] ----------
__global__ void proj_kernel(const float* __restrict__ h, const float* __restrict__ Wp,
                            float* __restrict__ ps, float* __restrict__ pd) {
    int idx = blockIdx.x * 256 + threadIdx.x;
    if (idx >= N_NODES * 4) return;
    int i = idx >> 2, c = idx & 3;
    const float* __restrict__ hr = h + (size_t)i * D_H;
    float a = 0.0f, b = 0.0f;
#pragma unroll 8
    for (int k = 0; k < D_H; ++k) {
        a += hr[k] * Wp[k * 4 + c];
        b += hr[k] * Wp[(D_H + k) * 4 + c];
    }
    ps[idx] = a;
    pd[idx] = b;
}

__global__ void edge_final_kernel(const int* __restrict__ srcv, const int* __restrict__ dstv,
                                  const float* __restrict__ ps, const float* __restrict__ pd,
                                  const float* __restrict__ bp, float* __restrict__ out) {
    int e = blockIdx.x * 256 + threadIdx.x;
    if (e >= N_EDGES) return;
    float4 a = reinterpret_cast<const float4*>(ps)[srcv[e]];
    float4 b = reinterpret_cast<const float4*>(pd)[dstv[e]];
    float4 o;
    o.x = a.x + b.x + bp[0];
    o.y = a.y + b.y + bp[1];
    o.z = a.z + b.z + bp[2];
    o.w = a.w + b.w + bp[3];
    reinterpret_cast<float4*>(out)[e] = o;
}

extern "C" void kernel_launch(void* const* d_in, const int* in_sizes, int n_in,
                              void* d_out, int out_size, void* d_ws, size_t ws_size,
                              hipStream_t stream) {
    const float* x   = (const float*)d_in[0];
    const int*   ei  = (const int*)d_in[1];
    const float* Wl1 = (const float*)d_in[2];
    const float* bl1 = (const float*)d_in[3];
    const float* Wr1 = (const float*)d_in[4];
    const float* Wl2 = (const float*)d_in[5];
    const float* bl2 = (const float*)d_in[6];
    const float* Wr2 = (const float*)d_in[7];
    const float* Wl3 = (const float*)d_in[8];
    const float* bl3 = (const float*)d_in[9];
    const float* Wr3 = (const float*)d_in[10];
    const float* Wp  = (const float*)d_in[11];
    const float* bp  = (const float*)d_in[12];
    float* out = (float*)d_out;

    const int* srcv = ei;
    const int* dstv = ei + N_EDGES;

    // ---- workspace carve-up ----
    int*   cnt       = (int*)d_ws;                     // 50000
    int*   blockSums = cnt + 50000;                    // 256
    int*   row_ptr   = blockSums + 256;                // 50001
    int*   cursor    = row_ptr + 50001;                // 50000
    int*   csr_src   = cursor + 50000;                 // 800000
    ushort* xb = (ushort*)(((uintptr_t)(csr_src + 800000) + 127) & ~(uintptr_t)127); // 6.4M
    ushort* Y  = xb + (size_t)N_NODES * D_IN;          // 3.2M bf16
    ushort* Hb = Y + (size_t)N_NODES * D_H;            // 3.2M bf16
    float* H1 = (float*)(((uintptr_t)(Hb + (size_t)N_NODES * D_H) + 15) & ~(uintptr_t)15);
    float* H2 = H1 + (size_t)N_NODES * D_H;            // 3.2M floats
    float* ps = H2 + (size_t)N_NODES * D_H;            // 200000
    float* pd = ps + (size_t)N_NODES * 4;              // 200000

    // ---- CSR build ----
    hipMemsetAsync(cnt, 0, N_NODES * sizeof(int), stream);
    hist_kernel<<<(N_EDGES + 255) / 256, 256, 0, stream>>>(dstv, cnt);
    scan_partial<<<SCAN_BLOCKS, 256, 0, stream>>>(cnt, blockSums);
    scan_sums<<<1, 256, 0, stream>>>(blockSums);
    scan_final<<<SCAN_BLOCKS, 256, 0, stream>>>(cnt, blockSums, row_ptr, cursor);
    fill_kernel<<<(N_EDGES + 255) / 256, 256, 0, stream>>>(srcv, dstv, cursor, csr_src);

    // ---- x -> bf16 ----
    cvt_bf16_kernel<<<(N_NODES * D_IN / 4 + 255) / 256, 256, 0, stream>>>(x, xb, N_NODES * D_IN / 4);

    const int GATHER_GRID = (N_NODES + 3) / 4;
    const int MFMA_GRID = 256;  // 1024 waves, grid-strided over 3125 M-tiles

    // ---- layer 1 (FIN=128) ----
    lin_mfma_kernel<D_IN><<<MFMA_GRID, 256, 0, stream>>>(xb, Wl1, Y);
    gather_kernel<D_IN><<<GATHER_GRID, 256, 0, stream>>>(Y, x, Wr1, bl1, row_ptr, csr_src, H1, Hb);

    // ---- layer 2 (FIN=64) ----
    lin_mfma_kernel<D_H><<<MFMA_GRID, 256, 0, stream>>>(Hb, Wl2, Y);
    gather_kernel<D_H><<<GATHER_GRID, 256, 0, stream>>>(Y, H1, Wr2, bl2, row_ptr, csr_src, H2, Hb);

    // ---- layer 3 (FIN=64) ----
    lin_mfma_kernel<D_H><<<MFMA_GRID, 256, 0, stream>>>(Hb, Wl3, Y);
    gather_kernel<D_H><<<GATHER_GRID, 256, 0, stream>>>(Y, H2, Wr3, bl3, row_ptr, csr_src, H1, Hb);

    // ---- edge output: out[e] = ps[src] + pd[dst] + bp ----
    proj_kernel<<<(N_NODES * 4 + 255) / 256, 256, 0, stream>>>(H1, Wp, ps, pd);
    edge_final_kernel<<<(N_EDGES + 255) / 256, 256, 0, stream>>>(srcv, dstv, ps, pd, bp, out);
}

// Round 5
// 329.727 us; speedup vs baseline: 3.9243x; 1.1945x over previous
//
#include <hip/hip_runtime.h>
#include <hip/hip_bf16.h>

#define N_NODES 50000
#define N_EDGES 800000
#define D_IN 128
#define D_H 64
#define SCAN_BLOCKS 196   // ceil(50000/256)

typedef short bf16x8 __attribute__((ext_vector_type(8)));
typedef float f32x4 __attribute__((ext_vector_type(4)));

__device__ __forceinline__ ushort f2bf(float f) {
    __hip_bfloat16 b = __float2bfloat16(f);
    return *reinterpret_cast<ushort*>(&b);
}
__device__ __forceinline__ float bf16_lo(unsigned int u) { return __uint_as_float(u << 16); }
__device__ __forceinline__ float bf16_hi(unsigned int u) { return __uint_as_float(u & 0xffff0000u); }

// ---------- CSR build ----------
__global__ void hist_kernel(const int* __restrict__ dstv, int* __restrict__ cnt) {
    int e = blockIdx.x * 256 + threadIdx.x;
    if (e < N_EDGES) atomicAdd(&cnt[dstv[e]], 1);
}

__global__ void scan_partial(const int* __restrict__ cnt, int* __restrict__ blockSums) {
    __shared__ int s[256];
    int i = blockIdx.x * 256 + threadIdx.x;
    s[threadIdx.x] = (i < N_NODES) ? cnt[i] : 0;
    __syncthreads();
    for (int off = 128; off > 0; off >>= 1) {
        if (threadIdx.x < off) s[threadIdx.x] += s[threadIdx.x + off];
        __syncthreads();
    }
    if (threadIdx.x == 0) blockSums[blockIdx.x] = s[0];
}

__global__ void scan_sums(int* __restrict__ blockSums) {
    __shared__ int s[256];
    int t = threadIdx.x;
    s[t] = (t < SCAN_BLOCKS) ? blockSums[t] : 0;
    __syncthreads();
    for (int off = 1; off < 256; off <<= 1) {
        int tmp = (t >= off) ? s[t - off] : 0;
        __syncthreads();
        s[t] += tmp;
        __syncthreads();
    }
    if (t < SCAN_BLOCKS) blockSums[t] = (t > 0) ? s[t - 1] : 0;
}

__global__ void scan_final(const int* __restrict__ cnt, const int* __restrict__ blockSums,
                           int* __restrict__ row_ptr, int* __restrict__ cursor) {
    __shared__ int s[256];
    int t = threadIdx.x;
    int i = blockIdx.x * 256 + t;
    s[t] = (i < N_NODES) ? cnt[i] : 0;
    __syncthreads();
    for (int off = 1; off < 256; off <<= 1) {
        int tmp = (t >= off) ? s[t - off] : 0;
        __syncthreads();
        s[t] += tmp;
        __syncthreads();
    }
    int excl = blockSums[blockIdx.x] + ((t > 0) ? s[t - 1] : 0);
    if (i < N_NODES) { row_ptr[i] = excl; cursor[i] = excl; }
    if (i == 0) row_ptr[N_NODES] = N_EDGES;
}

__global__ void fill_kernel(const int* __restrict__ srcv, const int* __restrict__ dstv,
                            int* __restrict__ cursor, int* __restrict__ csr_src) {
    int e = blockIdx.x * 256 + threadIdx.x;
    if (e < N_EDGES) {
        int pos = atomicAdd(&cursor[dstv[e]], 1);
        csr_src[pos] = srcv[e];
    }
}

// ---------- Y = bf16(h @ Wl), Z = f32(h @ Wr) via MFMA, fp32 input ----------
// wave = one 16-row M-tile (grid-strided), 4 n-tiles per product.
// A-frag: lane holds h[m0 + (lane&15)][kt*32 + (lane>>4)*8 + j], j=0..7 (2 x 16B fp32 load + cvt)
// B-frag: lane holds W[kt*32 + (lane>>4)*8 + j][nt*16 + (lane&15)] (built once, VGPR-resident)
// D:      lane holds out[m0 + (lane>>4)*4 + reg][nt*16 + (lane&15)]
template <int FIN>
__global__ void linYZ_kernel(const float* __restrict__ h, const float* __restrict__ Wl,
                             const float* __restrict__ Wr,
                             ushort* __restrict__ Y, float* __restrict__ Z) {
    constexpr int KT = FIN / 32;
    int wave = (blockIdx.x * 256 + threadIdx.x) >> 6;
    int lane = threadIdx.x & 63;
    int col = lane & 15;
    int quad = lane >> 4;
    int nwaves = gridDim.x * 4;

    bf16x8 bl_frag[KT][4], br_frag[KT][4];
#pragma unroll
    for (int kt = 0; kt < KT; ++kt)
#pragma unroll
        for (int nt = 0; nt < 4; ++nt) {
            bf16x8 tl, tr;
#pragma unroll
            for (int j = 0; j < 8; ++j) {
                int row = kt * 32 + quad * 8 + j;
                tl[j] = (short)f2bf(Wl[row * D_H + nt * 16 + col]);
                tr[j] = (short)f2bf(Wr[row * D_H + nt * 16 + col]);
            }
            bl_frag[kt][nt] = tl;
            br_frag[kt][nt] = tr;
        }

    for (int m0 = wave * 16; m0 < N_NODES; m0 += nwaves * 16) {
        f32x4 accl0 = {0.f,0.f,0.f,0.f}, accl1 = accl0, accl2 = accl0, accl3 = accl0;
        f32x4 accr0 = accl0, accr1 = accl0, accr2 = accl0, accr3 = accl0;
        const float* arow = h + (size_t)(m0 + col) * FIN + quad * 8;
#pragma unroll
        for (int kt = 0; kt < KT; ++kt) {
            float4 a_lo = *reinterpret_cast<const float4*>(arow + kt * 32);
            float4 a_hi = *reinterpret_cast<const float4*>(arow + kt * 32 + 4);
            bf16x8 a;
            a[0] = (short)f2bf(a_lo.x); a[1] = (short)f2bf(a_lo.y);
            a[2] = (short)f2bf(a_lo.z); a[3] = (short)f2bf(a_lo.w);
            a[4] = (short)f2bf(a_hi.x); a[5] = (short)f2bf(a_hi.y);
            a[6] = (short)f2bf(a_hi.z); a[7] = (short)f2bf(a_hi.w);
            accl0 = __builtin_amdgcn_mfma_f32_16x16x32_bf16(a, bl_frag[kt][0], accl0, 0, 0, 0);
            accl1 = __builtin_amdgcn_mfma_f32_16x16x32_bf16(a, bl_frag[kt][1], accl1, 0, 0, 0);
            accl2 = __builtin_amdgcn_mfma_f32_16x16x32_bf16(a, bl_frag[kt][2], accl2, 0, 0, 0);
            accl3 = __builtin_amdgcn_mfma_f32_16x16x32_bf16(a, bl_frag[kt][3], accl3, 0, 0, 0);
            accr0 = __builtin_amdgcn_mfma_f32_16x16x32_bf16(a, br_frag[kt][0], accr0, 0, 0, 0);
            accr1 = __builtin_amdgcn_mfma_f32_16x16x32_bf16(a, br_frag[kt][1], accr1, 0, 0, 0);
            accr2 = __builtin_amdgcn_mfma_f32_16x16x32_bf16(a, br_frag[kt][2], accr2, 0, 0, 0);
            accr3 = __builtin_amdgcn_mfma_f32_16x16x32_bf16(a, br_frag[kt][3], accr3, 0, 0, 0);
        }
#pragma unroll
        for (int reg = 0; reg < 4; ++reg) {
            size_t r = (size_t)(m0 + quad * 4 + reg) * D_H;
            ushort* yp = Y + r;
            yp[0 * 16 + col] = f2bf(accl0[reg]);
            yp[1 * 16 + col] = f2bf(accl1[reg]);
            yp[2 * 16 + col] = f2bf(accl2[reg]);
            yp[3 * 16 + col] = f2bf(accl3[reg]);
            float* zp = Z + r;
            zp[0 * 16 + col] = accr0[reg];
            zp[1 * 16 + col] = accr1[reg];
            zp[2 * 16 + col] = accr2[reg];
            zp[3 * 16 + col] = accr3[reg];
        }
    }
}

// ---------- per-node: agg = mean_{src} Y[src]; out = elu(agg + bl + Z[node]) ----------
// one wave per node; group g (of 4) handles edge k+4t+g, lane-chunk l covers
// features [4l,4l+4) via one 8-byte (4 x bf16) load. Row = 128 B = one cache line.
__global__ void gather_kernel(const ushort* __restrict__ Y, const float* __restrict__ Z,
                              const float* __restrict__ bl,
                              const int* __restrict__ row_ptr, const int* __restrict__ csr_src,
                              float* __restrict__ out) {
    int node = (blockIdx.x << 2) + (threadIdx.x >> 6);
    int lane = threadIdx.x & 63;
    if (node >= N_NODES) return;
    int g = lane >> 4;
    int l = lane & 15;

    int beg = row_ptr[node];
    int deg = row_ptr[node + 1] - beg;
    float a0 = 0.f, a1 = 0.f, a2 = 0.f, a3 = 0.f;
    const uint2* __restrict__ Y2 = reinterpret_cast<const uint2*>(Y);  // 16 uint2 per row

    for (int base = 0; base < deg; base += 64) {
        int wend = deg - base; if (wend > 64) wend = 64;
        int mye = base + lane;
        int idxv = (mye < deg) ? csr_src[beg + mye] : 0;
        for (int k = 0; k < wend; k += 16) {
            int e0 = k + g, e1 = k + 4 + g, e2 = k + 8 + g, e3 = k + 12 + g;
            int s0 = __shfl(idxv, e0);
            int s1 = __shfl(idxv, e1);
            int s2 = __shfl(idxv, e2);
            int s3 = __shfl(idxv, e3);
            bool v0 = e0 < wend, v1 = e1 < wend, v2 = e2 < wend, v3 = e3 < wend;
            uint2 r0, r1, r2, r3;
            if (v0) r0 = Y2[s0 * 16 + l];
            if (v1) r1 = Y2[s1 * 16 + l];
            if (v2) r2 = Y2[s2 * 16 + l];
            if (v3) r3 = Y2[s3 * 16 + l];
            if (v0) { a0 += bf16_lo(r0.x); a1 += bf16_hi(r0.x); a2 += bf16_lo(r0.y); a3 += bf16_hi(r0.y); }
            if (v1) { a0 += bf16_lo(r1.x); a1 += bf16_hi(r1.x); a2 += bf16_lo(r1.y); a3 += bf16_hi(r1.y); }
            if (v2) { a0 += bf16_lo(r2.x); a1 += bf16_hi(r2.x); a2 += bf16_lo(r2.y); a3 += bf16_hi(r2.y); }
            if (v3) { a0 += bf16_lo(r3.x); a1 += bf16_hi(r3.x); a2 += bf16_lo(r3.y); a3 += bf16_hi(r3.y); }
        }
    }

    a0 += __shfl_xor(a0, 16); a0 += __shfl_xor(a0, 32);
    a1 += __shfl_xor(a1, 16); a1 += __shfl_xor(a1, 32);
    a2 += __shfl_xor(a2, 16); a2 += __shfl_xor(a2, 32);
    a3 += __shfl_xor(a3, 16); a3 += __shfl_xor(a3, 32);

    if (g == 0) {
        float inv = 1.0f / fmaxf((float)deg, 1.0f);
        float4 b = reinterpret_cast<const float4*>(bl)[l];
        float4 zv = reinterpret_cast<const float4*>(Z + (size_t)node * D_H)[l];
        float v0 = a0 * inv + b.x + zv.x;
        float v1 = a1 * inv + b.y + zv.y;
        float v2 = a2 * inv + b.z + zv.z;
        float v3 = a3 * inv + b.w + zv.w;
        float4 o;
        o.x = v0 > 0.f ? v0 : expm1f(v0);
        o.y = v1 > 0.f ? v1 : expm1f(v1);
        o.z = v2 > 0.f ? v2 : expm1f(v2);
        o.w = v3 > 0.f ? v3 : expm1f(v3);
        reinterpret_cast<float4*>(out + (size_t)node * D_H)[l] = o;
    }
}

// ---------- ps = h @ Wp[0:64], pd = h @ Wp[64:128] ----------
__global__ void proj_kernel(const float* __restrict__ h, const float* __restrict__ Wp,
                            float* __restrict__ ps, float* __restrict__ pd) {
    int idx = blockIdx.x * 256 + threadIdx.x;
    if (idx >= N_NODES * 4) return;
    int i = idx >> 2, c = idx & 3;
    const float* __restrict__ hr = h + (size_t)i * D_H;
    float a = 0.0f, b = 0.0f;
#pragma unroll 8
    for (int k = 0; k < D_H; ++k) {
        a += hr[k] * Wp[k * 4 + c];
        b += hr[k] * Wp[(D_H + k) * 4 + c];
    }
    ps[idx] = a;
    pd[idx] = b;
}

__global__ void edge_final_kernel(const int* __restrict__ srcv, const int* __restrict__ dstv,
                                  const float* __restrict__ ps, const float* __restrict__ pd,
                                  const float* __restrict__ bp, float* __restrict__ out) {
    int e = blockIdx.x * 256 + threadIdx.x;
    if (e >= N_EDGES) return;
    float4 a = reinterpret_cast<const float4*>(ps)[srcv[e]];
    float4 b = reinterpret_cast<const float4*>(pd)[dstv[e]];
    float4 o;
    o.x = a.x + b.x + bp[0];
    o.y = a.y + b.y + bp[1];
    o.z = a.z + b.z + bp[2];
    o.w = a.w + b.w + bp[3];
    reinterpret_cast<float4*>(out)[e] = o;
}

extern "C" void kernel_launch(void* const* d_in, const int* in_sizes, int n_in,
                              void* d_out, int out_size, void* d_ws, size_t ws_size,
                              hipStream_t stream) {
    const float* x   = (const float*)d_in[0];
    const int*   ei  = (const int*)d_in[1];
    const float* Wl1 = (const float*)d_in[2];
    const float* bl1 = (const float*)d_in[3];
    const float* Wr1 = (const float*)d_in[4];
    const float* Wl2 = (const float*)d_in[5];
    const float* bl2 = (const float*)d_in[6];
    const float* Wr2 = (const float*)d_in[7];
    const float* Wl3 = (const float*)d_in[8];
    const float* bl3 = (const float*)d_in[9];
    const float* Wr3 = (const float*)d_in[10];
    const float* Wp  = (const float*)d_in[11];
    const float* bp  = (const float*)d_in[12];
    float* out = (float*)d_out;

    const int* srcv = ei;
    const int* dstv = ei + N_EDGES;

    // ---- workspace carve-up ----
    int*   cnt       = (int*)d_ws;                     // 50000
    int*   blockSums = cnt + 50000;                    // 256
    int*   row_ptr   = blockSums + 256;                // 50001
    int*   cursor    = row_ptr + 50001;                // 50000
    int*   csr_src   = cursor + 50000;                 // 800000
    ushort* Y = (ushort*)(((uintptr_t)(csr_src + 800000) + 127) & ~(uintptr_t)127); // 3.2M bf16
    float* Z  = (float*)(((uintptr_t)(Y + (size_t)N_NODES * D_H) + 15) & ~(uintptr_t)15); // 3.2M f
    float* H1 = Z + (size_t)N_NODES * D_H;             // 3.2M floats
    float* H2 = H1 + (size_t)N_NODES * D_H;            // 3.2M floats
    float* ps = H2 + (size_t)N_NODES * D_H;            // 200000
    float* pd = ps + (size_t)N_NODES * 4;              // 200000

    // ---- CSR build ----
    hipMemsetAsync(cnt, 0, N_NODES * sizeof(int), stream);
    hist_kernel<<<(N_EDGES + 255) / 256, 256, 0, stream>>>(dstv, cnt);
    scan_partial<<<SCAN_BLOCKS, 256, 0, stream>>>(cnt, blockSums);
    scan_sums<<<1, 256, 0, stream>>>(blockSums);
    scan_final<<<SCAN_BLOCKS, 256, 0, stream>>>(cnt, blockSums, row_ptr, cursor);
    fill_kernel<<<(N_EDGES + 255) / 256, 256, 0, stream>>>(srcv, dstv, cursor, csr_src);

    const int GATHER_GRID = (N_NODES + 3) / 4;
    const int MFMA_GRID = 256;  // 1024 waves, grid-strided over 3125 M-tiles

    // ---- layer 1 (FIN=128) ----
    linYZ_kernel<D_IN><<<MFMA_GRID, 256, 0, stream>>>(x, Wl1, Wr1, Y, Z);
    gather_kernel<<<GATHER_GRID, 256, 0, stream>>>(Y, Z, bl1, row_ptr, csr_src, H1);

    // ---- layer 2 (FIN=64) ----
    linYZ_kernel<D_H><<<MFMA_GRID, 256, 0, stream>>>(H1, Wl2, Wr2, Y, Z);
    gather_kernel<<<GATHER_GRID, 256, 0, stream>>>(Y, Z, bl2, row_ptr, csr_src, H2);

    // ---- layer 3 (FIN=64) ----
    linYZ_kernel<D_H><<<MFMA_GRID, 256, 0, stream>>>(H2, Wl3, Wr3, Y, Z);
    gather_kernel<<<GATHER_GRID, 256, 0, stream>>>(Y, Z, bl3, row_ptr, csr_src, H1);

    // ---- edge output: out[e] = ps[src] + pd[dst] + bp ----
    proj_kernel<<<(N_NODES * 4 + 255) / 256, 256, 0, stream>>>(H1, Wp, ps, pd);
    edge_final_kernel<<<(N_EDGES + 255) / 256, 256, 0, stream>>>(srcv, dstv, ps, pd, bp, out);
}